// Round 7
// baseline (1621.393 us; speedup 1.0000x reference)
//
#include <hip/hip_runtime.h>
#include <hip/hip_bf16.h>

#define L_NUM 20
#define CC 128
#define TB 8192
#define BB 8
#define TT 64

#define NCONV (L_NUM * 3 * 256 * 128)
#define NMAT  (L_NUM * 128 * 128)
#define XN    ((size_t)BB * TB * CC)   // elements per bf16 x plane

typedef __attribute__((ext_vector_type(4))) float f32x4;
typedef __attribute__((ext_vector_type(8))) short bf16x8;
typedef unsigned int u32;

#define MFMA16 __builtin_amdgcn_mfma_f32_16x16x32_bf16

static const int DILS[L_NUM] = {1, 2, 4, 8, 16, 32, 64, 128, 256, 512,
                                1, 2, 4, 8, 16, 32, 64, 128, 256, 512};

__device__ __forceinline__ unsigned short f2b(float f) {
  union { __hip_bfloat16 h; unsigned short u; } cv;
  cv.h = __float2bfloat16(f);
  return cv.u;
}
__device__ __forceinline__ float b2fu(u32 u) {
  union { u32 u; float f; } cv;
  cv.u = u << 16;
  return cv.f;
}

// byte offset into a [64 t][128 c] bf16 LDS tile, XOR-swizzled (G4)
__device__ __forceinline__ int swz(int t, int cbyte) {
  return (t * 256 + cbyte) ^ ((t & 7) << 4);
}

// async global->LDS, 16B per lane; LDS dest = wave-uniform base + lane*16
__device__ __forceinline__ void gload16(const void* g, void* l) {
  __builtin_amdgcn_global_load_lds(
      (const __attribute__((address_space(1))) u32*)g,
      (__attribute__((address_space(3))) u32*)l, 16, 0, 0);
}

__global__ void prep_kernel(const float* __restrict__ Wconv,
                            const float* __restrict__ Wout,
                            const float* __restrict__ Wskip,
                            unsigned short* __restrict__ wc,
                            unsigned short* __restrict__ wo,
                            unsigned short* __restrict__ wsk,
                            unsigned short* __restrict__ zp) {
  int i = blockIdx.x * 256 + threadIdx.x;
  if (i < 128) zp[i] = 0;
  if (i < NCONV) {
    // dst [l][k][o][c] <- src [l][o][c][k]
    int c = i & 127;
    int o = (i >> 7) & 255;
    int lk = i >> 15;
    int k = lk % 3;
    int l = lk / 3;
    wc[i] = f2b(Wconv[((size_t)(l * 256 + o) * 128 + c) * 3 + k]);
  }
  if (i < NMAT) {
    wo[i]  = f2b(Wout[i]);
    wsk[i] = f2b(Wskip[i]);
  }
}

// x0 f32 [B][C][T] -> hi/lo bf16 [B][T][C] (plain linear layout)
__global__ __launch_bounds__(256) void x0t_kernel(const float* __restrict__ x0,
                                                  unsigned short* __restrict__ hi,
                                                  unsigned short* __restrict__ lo) {
  __shared__ unsigned short Hs[64 * CC], Ls[64 * CC];
  const int tid = threadIdx.x, lane = tid & 63, w = tid >> 6;
  const int b = blockIdx.y, t0 = blockIdx.x * 64;
  const float* xb = x0 + (size_t)b * CC * TB;
#pragma unroll
  for (int it = 0; it < 8; ++it) {
    int c0 = it * 16 + w * 4;
    u32 hu[4], lu[4];
#pragma unroll
    for (int i2 = 0; i2 < 4; ++i2) {
      float v = xb[(size_t)(c0 + i2) * TB + t0 + lane];
      unsigned short h = f2b(v);
      hu[i2] = h;
      lu[i2] = f2b(v - b2fu(h));
    }
    uint2 hp, lp;
    hp.x = hu[0] | (hu[1] << 16); hp.y = hu[2] | (hu[3] << 16);
    lp.x = lu[0] | (lu[1] << 16); lp.y = lu[2] | (lu[3] << 16);
    *reinterpret_cast<uint2*>(reinterpret_cast<char*>(Hs) + swz(lane, c0 * 2)) = hp;
    *reinterpret_cast<uint2*>(reinterpret_cast<char*>(Ls) + swz(lane, c0 * 2)) = lp;
  }
  __syncthreads();
  unsigned short* hb = hi + ((size_t)b * TB + t0) * CC;
  unsigned short* lb = lo + ((size_t)b * TB + t0) * CC;
#pragma unroll
  for (int it = 0; it < 4; ++it) {
    int o = it * 4096 + tid * 16;
    int t = o >> 8;
    int cl = o & 255;
    int li = t * 256 + (cl ^ ((t & 7) << 4));
    *reinterpret_cast<f32x4*>(reinterpret_cast<char*>(hb) + (size_t)t * 256 + cl) =
        *reinterpret_cast<f32x4*>(reinterpret_cast<char*>(Hs) + li);
    *reinterpret_cast<f32x4*>(reinterpret_cast<char*>(lb) + (size_t)t * 256 + cl) =
        *reinterpret_cast<f32x4*>(reinterpret_cast<char*>(Ls) + li);
  }
}

// ---------------- K1: dilated conv + gated activation -> z plane ----------------
// 4 waves; wave w owns conv rows [32w,32w+32) of A-half and G-half.
// Taps 0/1 staged in LDS (32 KB); tap 2 (own window) read direct from global.
// ONE barrier. Output: z bf16 [B][T][C].
__global__ __launch_bounds__(256, 3) void conv_kernel(
    const unsigned short* __restrict__ hin,   // [B][T][C] bf16 hi plane
    unsigned short* __restrict__ zout,        // [B][T][C] bf16 z plane
    const unsigned short* __restrict__ zpage, // 256B zeros
    const unsigned short* __restrict__ Wc,    // [3][256][128] bf16
    const float* __restrict__ bconv,          // [256]
    int dil) {
  __shared__ unsigned short Xs[2][TT * CC];   // taps 0,1

  const int tid = threadIdx.x;
  const int lane = tid & 63;
  const int w = tid >> 6;
  const int lo16 = lane & 15;
  const int hi4 = lane >> 4;

  // XCD-aware remap: each XCD owns a contiguous 1024-t window
  int p = blockIdx.x;               // 0..127
  int xcd = p & 7, ii = p >> 3;
  int t0 = (xcd * 16 + ii) * TT;
  int b = blockIdx.y;

  const unsigned short* hb = hin + (size_t)b * TB * CC;

  // stage taps 0,1 via global_load_lds (linear LDS, pre-swizzled source)
#pragma unroll
  for (int k = 0; k < 2; ++k) {
    int tbase = t0 + (k - 2) * dil;
#pragma unroll
    for (int i = 0; i < 4; ++i) {
      int o = w * 4096 + i * 1024 + lane * 16;
      int tl = o >> 8;
      int cb = (o & 255) ^ ((tl & 7) << 4);
      int tg = tbase + tl;
      const char* src = (tg >= 0)
          ? (reinterpret_cast<const char*>(hb + (size_t)tg * CC) + cb)
          : (reinterpret_cast<const char*>(zpage) + cb);
      gload16(src, reinterpret_cast<char*>(&Xs[k][0]) + o);
    }
  }

  f32x4 zero4 = {0.f, 0.f, 0.f, 0.f};
  f32x4 accA[2][4], accG[2][4];
#pragma unroll
  for (int r = 0; r < 2; ++r)
#pragma unroll
    for (int j = 0; j < 4; ++j) { accA[r][j] = zero4; accG[r][j] = zero4; }

  // ---- tap 2 first: B-frags direct from global (own window, L2-hot)
  {
    const unsigned short* Wk = Wc + 2 * 256 * 128;
#pragma unroll
    for (int kk = 0; kk < 4; ++kk) {
      int c0 = kk * 32 + hi4 * 8;
      bf16x8 aA0 = *reinterpret_cast<const bf16x8*>(Wk + (w * 32 + lo16) * 128 + c0);
      bf16x8 aA1 = *reinterpret_cast<const bf16x8*>(Wk + (w * 32 + 16 + lo16) * 128 + c0);
      bf16x8 aG0 = *reinterpret_cast<const bf16x8*>(Wk + (128 + w * 32 + lo16) * 128 + c0);
      bf16x8 aG1 = *reinterpret_cast<const bf16x8*>(Wk + (128 + w * 32 + 16 + lo16) * 128 + c0);
#pragma unroll
      for (int j = 0; j < 4; ++j) {
        bf16x8 bx8 = *reinterpret_cast<const bf16x8*>(
            hb + (size_t)(t0 + j * 16 + lo16) * CC + c0);
        accA[0][j] = MFMA16(aA0, bx8, accA[0][j], 0, 0, 0);
        accA[1][j] = MFMA16(aA1, bx8, accA[1][j], 0, 0, 0);
        accG[0][j] = MFMA16(aG0, bx8, accG[0][j], 0, 0, 0);
        accG[1][j] = MFMA16(aG1, bx8, accG[1][j], 0, 0, 0);
      }
    }
  }

  __syncthreads();  // taps 0,1 resident (the only barrier)

#pragma unroll
  for (int k = 0; k < 2; ++k) {
    const unsigned short* Wk = Wc + k * 256 * 128;
#pragma unroll
    for (int kk = 0; kk < 4; ++kk) {
      int c0 = kk * 32 + hi4 * 8;
      bf16x8 aA0 = *reinterpret_cast<const bf16x8*>(Wk + (w * 32 + lo16) * 128 + c0);
      bf16x8 aA1 = *reinterpret_cast<const bf16x8*>(Wk + (w * 32 + 16 + lo16) * 128 + c0);
      bf16x8 aG0 = *reinterpret_cast<const bf16x8*>(Wk + (128 + w * 32 + lo16) * 128 + c0);
      bf16x8 aG1 = *reinterpret_cast<const bf16x8*>(Wk + (128 + w * 32 + 16 + lo16) * 128 + c0);
#pragma unroll
      for (int j = 0; j < 4; ++j) {
        bf16x8 bx8 = *reinterpret_cast<const bf16x8*>(
            reinterpret_cast<const char*>(&Xs[k][0]) + swz(j * 16 + lo16, c0 * 2));
        accA[0][j] = MFMA16(aA0, bx8, accA[0][j], 0, 0, 0);
        accA[1][j] = MFMA16(aA1, bx8, accA[1][j], 0, 0, 0);
        accG[0][j] = MFMA16(aG0, bx8, accG[0][j], 0, 0, 0);
        accG[1][j] = MFMA16(aG1, bx8, accG[1][j], 0, 0, 0);
      }
    }
  }

  // gated activation -> z store (direct, [t][c] uint2 per thread)
  unsigned short* zb = zout + (size_t)b * TB * CC;
#pragma unroll
  for (int r = 0; r < 2; ++r) {
    int cB = w * 32 + r * 16 + hi4 * 4;
    f32x4 bca = *reinterpret_cast<const f32x4*>(bconv + cB);
    f32x4 bcg = *reinterpret_cast<const f32x4*>(bconv + 128 + cB);
#pragma unroll
    for (int j = 0; j < 4; ++j) {
      u32 zu[4];
#pragma unroll
      for (int reg = 0; reg < 4; ++reg) {
        float a = accA[r][j][reg] + bca[reg];
        float g = accG[r][j][reg] + bcg[reg];
        float ea = __builtin_amdgcn_exp2f(2.885390081777927f * a);   // e^{2a}
        float th = 1.f - 2.f * __builtin_amdgcn_rcpf(1.f + ea);       // tanh(a)
        float sg = __builtin_amdgcn_rcpf(
            1.f + __builtin_amdgcn_exp2f(-1.4426950408889634f * g));  // sigmoid
        zu[reg] = f2b(th * sg);
      }
      uint2 pz;
      pz.x = zu[0] | (zu[1] << 16);
      pz.y = zu[2] | (zu[3] << 16);
      *reinterpret_cast<uint2*>(zb + (size_t)(t0 + j * 16 + lo16) * CC + cB) = pz;
    }
  }
}

// ---------------- K2: skip GEMM + out GEMM + residual, streaming ----------------
// No LDS, no barriers. z B-frags read direct from the L2-hot z plane.
// Phase 1: S-GEMM -> nt skip stores. Phase 2: O-GEMM -> in-place hi/lo update
// (or, last layer, fx = z + hi + lo).
__global__ __launch_bounds__(256, 4) void post_kernel(
    const unsigned short* __restrict__ zin,   // [B][T][C] bf16 z plane
    unsigned short* __restrict__ hio,         // [B][T][C] bf16 hi plane (in-place)
    unsigned short* __restrict__ loo,         // [B][T][C] bf16 lo plane (in-place)
    const unsigned short* __restrict__ Wo,    // [128][128] bf16
    const float* __restrict__ bout,           // [128]
    const unsigned short* __restrict__ Wsk,   // [128][128] bf16
    const float* __restrict__ bskip,          // [128]
    float* __restrict__ skipo,                // [B][S][T] f32 slice
    float* __restrict__ fxout,                // [B][C][T] f32 (last only)
    int last) {
  const int tid = threadIdx.x;
  const int lane = tid & 63;
  const int w = tid >> 6;
  const int lo16 = lane & 15;
  const int hi4 = lane >> 4;

  int p = blockIdx.x;               // same swizzle as conv_kernel (z stays on-XCD)
  int xcd = p & 7, ii = p >> 3;
  int t0 = (xcd * 16 + ii) * TT;
  int b = blockIdx.y;

  const unsigned short* zb = zin + (size_t)b * TB * CC;
  unsigned short* hbp = hio + (size_t)b * TB * CC;
  unsigned short* lbp = loo + (size_t)b * TB * CC;
  float* skb = skipo + (size_t)b * CC * TB;
  float* fxb = fxout + (size_t)b * CC * TB;

  f32x4 zero4 = {0.f, 0.f, 0.f, 0.f};

  // ---- phase 1: skip GEMM + nt stores
  f32x4 accS[2][4];
#pragma unroll
  for (int r = 0; r < 2; ++r)
#pragma unroll
    for (int j = 0; j < 4; ++j) accS[r][j] = zero4;

#pragma unroll
  for (int kk = 0; kk < 4; ++kk) {
    int c0 = kk * 32 + hi4 * 8;
    bf16x8 aS0 = *reinterpret_cast<const bf16x8*>(Wsk + (w * 32 + lo16) * 128 + c0);
    bf16x8 aS1 = *reinterpret_cast<const bf16x8*>(Wsk + (w * 32 + 16 + lo16) * 128 + c0);
#pragma unroll
    for (int j = 0; j < 4; ++j) {
      bf16x8 bz = *reinterpret_cast<const bf16x8*>(
          zb + (size_t)(t0 + j * 16 + lo16) * CC + c0);
      accS[0][j] = MFMA16(aS0, bz, accS[0][j], 0, 0, 0);
      accS[1][j] = MFMA16(aS1, bz, accS[1][j], 0, 0, 0);
    }
  }
#pragma unroll
  for (int r = 0; r < 2; ++r) {
    int cB = w * 32 + r * 16 + hi4 * 4;
    f32x4 bsk = *reinterpret_cast<const f32x4*>(bskip + cB);
#pragma unroll
    for (int j = 0; j < 4; ++j) {
      int t = j * 16 + lo16;
#pragma unroll
      for (int reg = 0; reg < 4; ++reg)
        __builtin_nontemporal_store(accS[r][j][reg] + bsk[reg],
                                    skb + (size_t)(cB + reg) * TB + t0 + t);
    }
  }

  // ---- phase 2: residual
  // prefetch hi/lo (consumed after O-GEMM / for fx)
  uint2 hres[2][4], lres[2][4];
#pragma unroll
  for (int r = 0; r < 2; ++r) {
    int cB = w * 32 + r * 16 + hi4 * 4;
#pragma unroll
    for (int j = 0; j < 4; ++j) {
      int t = t0 + j * 16 + lo16;
      hres[r][j] = *reinterpret_cast<const uint2*>(hbp + (size_t)t * CC + cB);
      lres[r][j] = *reinterpret_cast<const uint2*>(lbp + (size_t)t * CC + cB);
    }
  }

  if (!last) {
    f32x4 accO[2][4];
#pragma unroll
    for (int r = 0; r < 2; ++r)
#pragma unroll
      for (int j = 0; j < 4; ++j) accO[r][j] = zero4;

#pragma unroll
    for (int kk = 0; kk < 4; ++kk) {
      int c0 = kk * 32 + hi4 * 8;
      bf16x8 aO0 = *reinterpret_cast<const bf16x8*>(Wo + (w * 32 + lo16) * 128 + c0);
      bf16x8 aO1 = *reinterpret_cast<const bf16x8*>(Wo + (w * 32 + 16 + lo16) * 128 + c0);
#pragma unroll
      for (int j = 0; j < 4; ++j) {
        bf16x8 bz = *reinterpret_cast<const bf16x8*>(
            zb + (size_t)(t0 + j * 16 + lo16) * CC + c0);
        accO[0][j] = MFMA16(aO0, bz, accO[0][j], 0, 0, 0);
        accO[1][j] = MFMA16(aO1, bz, accO[1][j], 0, 0, 0);
      }
    }

#pragma unroll
    for (int r = 0; r < 2; ++r) {
      int cB = w * 32 + r * 16 + hi4 * 4;
      f32x4 bo = *reinterpret_cast<const f32x4*>(bout + cB);
#pragma unroll
      for (int j = 0; j < 4; ++j) {
        int t = t0 + j * 16 + lo16;
        u32 hu[4] = {hres[r][j].x & 0xffffu, hres[r][j].x >> 16,
                     hres[r][j].y & 0xffffu, hres[r][j].y >> 16};
        u32 lu[4] = {lres[r][j].x & 0xffffu, lres[r][j].x >> 16,
                     lres[r][j].y & 0xffffu, lres[r][j].y >> 16};
        u32 hn[4], ln[4];
#pragma unroll
        for (int reg = 0; reg < 4; ++reg) {
          float v = accO[r][j][reg] + bo[reg] + b2fu(hu[reg]) + b2fu(lu[reg]);
          unsigned short h = f2b(v);
          hn[reg] = h;
          ln[reg] = f2b(v - b2fu(h));
        }
        uint2 hq, lq;
        hq.x = hn[0] | (hn[1] << 16); hq.y = hn[2] | (hn[3] << 16);
        lq.x = ln[0] | (ln[1] << 16); lq.y = ln[2] | (ln[3] << 16);
        *reinterpret_cast<uint2*>(hbp + (size_t)t * CC + cB) = hq;  // in-place
        *reinterpret_cast<uint2*>(lbp + (size_t)t * CC + cB) = lq;  // in-place
      }
    }
  } else {
    // fx = z + hi + lo, f32 [B][C][T]
#pragma unroll
    for (int r = 0; r < 2; ++r) {
      int cB = w * 32 + r * 16 + hi4 * 4;
#pragma unroll
      for (int j = 0; j < 4; ++j) {
        int t = t0 + j * 16 + lo16;
        uint2 zp2 = *reinterpret_cast<const uint2*>(zb + (size_t)t * CC + cB);
        u32 zu[4] = {zp2.x & 0xffffu, zp2.x >> 16, zp2.y & 0xffffu, zp2.y >> 16};
        u32 hu[4] = {hres[r][j].x & 0xffffu, hres[r][j].x >> 16,
                     hres[r][j].y & 0xffffu, hres[r][j].y >> 16};
        u32 lu[4] = {lres[r][j].x & 0xffffu, lres[r][j].x >> 16,
                     lres[r][j].y & 0xffffu, lres[r][j].y >> 16};
#pragma unroll
        for (int reg = 0; reg < 4; ++reg)
          __builtin_nontemporal_store(
              b2fu(zu[reg]) + b2fu(hu[reg]) + b2fu(lu[reg]),
              fxb + (size_t)(cB + reg) * TB + t);
      }
    }
  }
}

extern "C" void kernel_launch(void* const* d_in, const int* in_sizes, int n_in,
                              void* d_out, int out_size, void* d_ws, size_t ws_size,
                              hipStream_t stream) {
  const float* x0    = (const float*)d_in[0];
  const float* Wconv = (const float*)d_in[1];
  const float* bconv = (const float*)d_in[2];
  const float* Wout  = (const float*)d_in[3];
  const float* bout  = (const float*)d_in[4];
  const float* Wskip = (const float*)d_in[5];
  const float* bskip = (const float*)d_in[6];

  unsigned short* wc  = (unsigned short*)d_ws;   // [L][3][256][128] bf16
  unsigned short* wo  = wc + NCONV;              // [L][128][128] bf16
  unsigned short* wsk = wo + NMAT;               // [L][128][128] bf16
  unsigned short* zp  = wsk + NMAT;              // 256B zero page
  unsigned short* hi  = zp + 128;                // [B][T][C] bf16 hi plane
  unsigned short* lo  = hi + XN;                 // [B][T][C] bf16 lo plane
  unsigned short* zpl = lo + XN;                 // [B][T][C] bf16 z plane
  // ws total ~= 55.7 MB

  float* fx = (float*)d_out;                      // final x [B][C][T] f32
  float* skips = fx + XN;                         // [L][B][S][T] f32

  prep_kernel<<<(NCONV + 255) / 256, 256, 0, stream>>>(Wconv, Wout, Wskip, wc, wo, wsk, zp);
  x0t_kernel<<<dim3(TB / 64, BB), 256, 0, stream>>>(x0, hi, lo);

  for (int l = 0; l < L_NUM; ++l) {
    conv_kernel<<<dim3(TB / TT, BB), 256, 0, stream>>>(
        hi, zpl, zp,
        wc + (size_t)l * 3 * 256 * 128, bconv + (size_t)l * 256, DILS[l]);
    post_kernel<<<dim3(TB / TT, BB), 256, 0, stream>>>(
        zpl, hi, lo,
        wo + (size_t)l * 128 * 128, bout + (size_t)l * 128,
        wsk + (size_t)l * 128 * 128, bskip + (size_t)l * 128,
        skips + (size_t)l * XN, fx,
        l == L_NUM - 1 ? 1 : 0);
  }
}